// Round 1
// baseline (104.221 us; speedup 1.0000x reference)
//
#include <hip/hip_runtime.h>

typedef _Float16 half8 __attribute__((ext_vector_type(8)));
typedef _Float16 half4 __attribute__((ext_vector_type(4)));
typedef float floatx4 __attribute__((ext_vector_type(4)));

#define BB 8
#define NN 64
#define DD 64
#define EE 32

// ---------------- prep: fp32 -> fp16 conversions ----------------
// WT[d][k] = W_e[k][d]  (4096 x 32 fp16, A-operand friendly: k contiguous)
// Eh[b][e][k] = edges   (8*4096 x 32 fp16, B-operand friendly)
__global__ void prep_kernel(const float* __restrict__ W_e,
                            const float* __restrict__ edges,
                            _Float16* __restrict__ WT,
                            _Float16* __restrict__ Eh) {
    int blk = blockIdx.x;
    if (blk < 16) {
        int d = blk * 256 + threadIdx.x;      // 0..4095
        half8 buf[4];
#pragma unroll
        for (int k = 0; k < 32; ++k) {
            float v = W_e[k * 4096 + d];      // coalesced across lanes
            buf[k >> 3][k & 7] = (_Float16)v;
        }
#pragma unroll
        for (int q = 0; q < 4; ++q)
            *reinterpret_cast<half8*>(WT + d * 32 + q * 8) = buf[q];
    } else {
        int idx = ((blk - 16) * 256 + threadIdx.x) * 4;  // 1024 blocks cover 1,048,576
        floatx4 v = *reinterpret_cast<const floatx4*>(edges + idx);
        half4 h;
        h[0] = (_Float16)v[0]; h[1] = (_Float16)v[1];
        h[2] = (_Float16)v[2]; h[3] = (_Float16)v[3];
        *reinterpret_cast<half4*>(Eh + idx) = h;
    }
}

// ---------------- main: fused A-GEMM + relu + message + mask + j-sum ----------------
// One workgroup per (b, i_node). 4 waves; wave w owns jj-block w (16 of 64 jj).
// Per i (message dim 0..63):
//   C[d=i*64+jj, e] = b_e[d] + sum_k WT[d][k] * Eh[e][k]      (4 MFMAs, e-blocks)
//   s_lane = sum over lane's 16 C elems of relu(C) * mask[e]*nodes[j(e)][jj]
// agg[b,i_node,i] = total sum over all lanes/waves.
__global__ __launch_bounds__(256, 2)
void mp_kernel(const _Float16* __restrict__ WT,
               const _Float16* __restrict__ Eh,
               const float* __restrict__ nodes,
               const float* __restrict__ mask,
               const float* __restrict__ b_e,
               float* __restrict__ agg) {
    const int b     = blockIdx.x >> 6;
    const int inode = blockIdx.x & 63;
    const int tid   = threadIdx.x;
    const int w     = tid >> 6;
    const int lane  = tid & 63;
    const int quad  = lane >> 4;
    const int col   = lane & 15;

    __shared__ float S[4][64][33];   // [wave][i][lane<32 after pair-reduce]
    __shared__ float P[4][64];

    // B-operand fragments: edges for e-blocks 0..3 (loop-invariant, 16 VGPRs)
    half8 ef[4];
#pragma unroll
    for (int eb = 0; eb < 4; ++eb) {
        int ge = b * 4096 + inode * 64 + eb * 16 + col;
        ef[eb] = *reinterpret_cast<const half8*>(Eh + ge * 32 + quad * 8);
    }

    // epilogue multipliers: xm[eb][r] = mask[e] * nodes[j(e)][jj]  (loop-invariant, 16 VGPRs)
    // C layout (16x16x32): col = lane&15 (e), row = quad*4+r (d within tile)
    float xm[4][4];
#pragma unroll
    for (int eb = 0; eb < 4; ++eb) {
        int j = eb * 16 + col;
        float mk = mask[b * 4096 + inode * 64 + j];
#pragma unroll
        for (int r = 0; r < 4; ++r) {
            int jj = w * 16 + quad * 4 + r;
            xm[eb][r] = mk * nodes[(b * 64 + j) * 64 + jj];
        }
    }

    // A-operand: WT rows d = i*64 + w*16 + col, k = quad*8 + j
    const _Float16* aptr = WT + (w * 16 + col) * 32 + quad * 8;   // +i*64*32 per i
    const float*    bptr = b_e + w * 16 + quad * 4;               // +i*64 per i

    half8  af = *reinterpret_cast<const half8*>(aptr);
    floatx4 bf = *reinterpret_cast<const floatx4*>(bptr);

    for (int i = 0; i < 64; ++i) {
        int inx = (i + 1) & 63;  // wrap: iter 63 reloads i=0 (harmless, branch-free)
        half8  af_n = *reinterpret_cast<const half8*>(aptr + inx * 64 * 32);
        floatx4 bf_n = *reinterpret_cast<const floatx4*>(bptr + inx * 64);

        floatx4 c0 = __builtin_amdgcn_mfma_f32_16x16x32_f16(af, ef[0], bf, 0, 0, 0);
        floatx4 c1 = __builtin_amdgcn_mfma_f32_16x16x32_f16(af, ef[1], bf, 0, 0, 0);
        floatx4 c2 = __builtin_amdgcn_mfma_f32_16x16x32_f16(af, ef[2], bf, 0, 0, 0);
        floatx4 c3 = __builtin_amdgcn_mfma_f32_16x16x32_f16(af, ef[3], bf, 0, 0, 0);

        float s = 0.f;
#pragma unroll
        for (int r = 0; r < 4; ++r) {
            s += fmaxf(c0[r], 0.f) * xm[0][r];
            s += fmaxf(c1[r], 0.f) * xm[1][r];
            s += fmaxf(c2[r], 0.f) * xm[2][r];
            s += fmaxf(c3[r], 0.f) * xm[3][r];
        }
        s += __shfl_xor(s, 32);          // pair-reduce: lanes 0..31 hold lane + lane^32
        if (lane < 32) S[w][i][lane] = s;

        af = af_n; bf = bf_n;
    }
    __syncthreads();

    {   // 256 threads: (w = tid>>6, i = tid&63) each sum 32 lane-partials
        int i = tid & 63, ww = tid >> 6;
        float p = 0.f;
#pragma unroll
        for (int l = 0; l < 32; ++l) p += S[ww][i][l];
        P[ww][i] = p;
    }
    __syncthreads();
    if (tid < 64)
        agg[(b * 64 + inode) * 64 + tid] = P[0][tid] + P[1][tid] + P[2][tid] + P[3][tid];
}

// ---------------- GRU: h = gru(agg, gru(nodes, 0)) ----------------
__device__ __forceinline__ float sigmoidf_(float x) {
    return 1.f / (1.f + __expf(-x));
}
__device__ __forceinline__ float tanhf_(float x) {
    float e = __expf(2.f * x);
    return (e - 1.f) / (e + 1.f);
}

__global__ void gru_kernel(const float* __restrict__ nodes,
                           const float* __restrict__ agg,
                           const float* __restrict__ K,
                           const float* __restrict__ R,
                           const float* __restrict__ bias,
                           float* __restrict__ out) {
    const int row = blockIdx.x;   // 0..511
    const int d   = threadIdx.x;  // 0..63
    __shared__ float xs[64], h1s[64], x2s[64];
    xs[d]  = nodes[row * 64 + d];
    x2s[d] = agg[row * 64 + d];
    __syncthreads();

    // step 1: h_prev = 0 -> hk = bias[1]
    float xz = bias[d], xr = bias[64 + d], xh = bias[128 + d];
    for (int k = 0; k < 64; ++k) {
        float xv = xs[k];
        xz = fmaf(xv, K[k * 192 + d], xz);
        xr = fmaf(xv, K[k * 192 + 64 + d], xr);
        xh = fmaf(xv, K[k * 192 + 128 + d], xh);
    }
    float hz = bias[192 + d], hr = bias[256 + d], hh0 = bias[320 + d];
    float z = sigmoidf_(xz + hz);
    float r = sigmoidf_(xr + hr);
    float hh = tanhf_(xh + r * hh0);
    float h = (1.f - z) * hh;   // z*h_prev = 0
    h1s[d] = h;
    __syncthreads();

    // step 2: x = agg, h_prev = h1
    xz = bias[d]; xr = bias[64 + d]; xh = bias[128 + d];
    hz = bias[192 + d]; hr = bias[256 + d]; hh0 = bias[320 + d];
    for (int k = 0; k < 64; ++k) {
        float xv = x2s[k], hv = h1s[k];
        xz = fmaf(xv, K[k * 192 + d], xz);
        xr = fmaf(xv, K[k * 192 + 64 + d], xr);
        xh = fmaf(xv, K[k * 192 + 128 + d], xh);
        hz = fmaf(hv, R[k * 192 + d], hz);
        hr = fmaf(hv, R[k * 192 + 64 + d], hr);
        hh0 = fmaf(hv, R[k * 192 + 128 + d], hh0);
    }
    float z2 = sigmoidf_(xz + hz);
    float r2 = sigmoidf_(xr + hr);
    float hh2 = tanhf_(xh + r2 * hh0);
    out[row * 64 + d] = z2 * h + (1.f - z2) * hh2;
}

extern "C" void kernel_launch(void* const* d_in, const int* in_sizes, int n_in,
                              void* d_out, int out_size, void* d_ws, size_t ws_size,
                              hipStream_t stream) {
    const float* nodes = (const float*)d_in[0];
    const float* edges = (const float*)d_in[1];
    const float* mask  = (const float*)d_in[2];
    const float* W_e   = (const float*)d_in[3];
    const float* b_e   = (const float*)d_in[4];
    const float* gk    = (const float*)d_in[5];
    const float* gr    = (const float*)d_in[6];
    const float* gb    = (const float*)d_in[7];
    float* out = (float*)d_out;

    char* ws = (char*)d_ws;
    _Float16* WT = (_Float16*)ws;                         // 4096*32*2   = 256 KB
    _Float16* Eh = (_Float16*)(ws + 262144);              // 32768*32*2  = 2 MB
    float*    agg = (float*)(ws + 262144 + 2097152);      // 32768*4     = 128 KB

    prep_kernel<<<1040, 256, 0, stream>>>(W_e, edges, WT, Eh);
    mp_kernel<<<512, 256, 0, stream>>>(WT, Eh, nodes, mask, b_e, agg);
    gru_kernel<<<512, 64, 0, stream>>>(nodes, agg, gk, gr, gb, out);
}

// Round 2
// 99.965 us; speedup vs baseline: 1.0426x; 1.0426x over previous
//
#include <hip/hip_runtime.h>

typedef _Float16 half8 __attribute__((ext_vector_type(8)));
typedef float floatx4 __attribute__((ext_vector_type(4)));
typedef float floatx2 __attribute__((ext_vector_type(2)));

#define BB 8
#define NN 64
#define DD 64
#define EE 32

// ---------------- prep: W_e (32 x 4096 fp32) -> WT (4096 x 32 fp16) ----------------
// WT[d][k] = W_e[k][d]; A-operand friendly (k contiguous per d).
// grid 64 x 256: block handles d-range [blk*64, blk*64+64); thread = (d0 = tid&63, kq = tid>>6).
__global__ void prep_w_kernel(const float* __restrict__ W_e,
                              _Float16* __restrict__ WT) {
    const int d  = blockIdx.x * 64 + (threadIdx.x & 63);
    const int kq = threadIdx.x >> 6;          // 0..3 -> k = kq*8 + j
    half8 buf;
#pragma unroll
    for (int j = 0; j < 8; ++j)
        buf[j] = (_Float16)W_e[(kq * 8 + j) * 4096 + d];   // coalesced across d
    *reinterpret_cast<half8*>(WT + d * 32 + kq * 8) = buf; // coalesced 16B stores
}

__device__ __forceinline__ floatx2 relu2(floatx2 v) {
    floatx2 z = {0.f, 0.f};
    return __builtin_elementwise_max(v, z);
}
__device__ __forceinline__ float sigmoidf_(float x) { return 1.f / (1.f + __expf(-x)); }
__device__ __forceinline__ float tanhf_(float x) {
    float e = __expf(2.f * x);
    return (e - 1.f) / (e + 1.f);
}

// ---------------- fused: A-GEMM + relu + message + mask + j-sum + 2-step GRU ----------------
// One block per (b, i_node) = one output row. 4 waves; wave w owns jj-block w.
// Per i (0..63): C[d=i*64+jj, e] = b_e[d] + sum_k WT[d][k]*E[e][k]  (4 MFMAs/wave)
// s_lane = sum relu(C)*mask[e]*nodes[j(e)][jj]; 2 shfl folds -> 16 partials -> LDS.
// Tail: cross-wave reduce -> agg row in LDS -> 2-step GRU -> out row.
__global__ __launch_bounds__(256, 2)
void fused_kernel(const _Float16* __restrict__ WT,
                  const float* __restrict__ edges,
                  const float* __restrict__ nodes,
                  const float* __restrict__ mask,
                  const float* __restrict__ b_e,
                  const float* __restrict__ K,
                  const float* __restrict__ R,
                  const float* __restrict__ bias,
                  float* __restrict__ out) {
    const int b     = blockIdx.x >> 6;
    const int inode = blockIdx.x & 63;
    const int tid   = threadIdx.x;
    const int w     = tid >> 6;
    const int lane  = tid & 63;
    const int quad  = lane >> 4;
    const int col   = lane & 15;
    const int row   = b * 64 + inode;         // GRU row = b*N + inode

    __shared__ float S[4][64][17];            // 17 KB: 16 col-partials per (wave, i)
    __shared__ float P[4][64];
    __shared__ float xs[64], aggs[64], h1s[64];
    __shared__ float g1[192], g2[192];

    if (tid < 64) xs[tid] = nodes[row * 64 + tid];

    // B-operand fragments from fp32 edges, converted in-register (loop-invariant)
    half8 ef[4];
#pragma unroll
    for (int eb = 0; eb < 4; ++eb) {
        const float* ep = edges + (b * 4096 + inode * 64 + eb * 16 + col) * 32 + quad * 8;
        floatx4 e0 = *reinterpret_cast<const floatx4*>(ep);
        floatx4 e1 = *reinterpret_cast<const floatx4*>(ep + 4);
#pragma unroll
        for (int j = 0; j < 4; ++j) {
            ef[eb][j]     = (_Float16)e0[j];
            ef[eb][4 + j] = (_Float16)e1[j];
        }
    }

    // epilogue multipliers: xm[eb][rp] = {mask*nodes for r=2rp, 2rp+1} (loop-invariant)
    floatx2 xm[4][2];
#pragma unroll
    for (int eb = 0; eb < 4; ++eb) {
        int j = eb * 16 + col;
        float mk = mask[b * 4096 + inode * 64 + j];
#pragma unroll
        for (int r = 0; r < 4; ++r) {
            int jj = w * 16 + quad * 4 + r;
            xm[eb][r >> 1][r & 1] = mk * nodes[(b * 64 + j) * 64 + jj];
        }
    }

    // A-operand: WT rows d = i*64 + w*16 + col, k = quad*8 + j  (contiguous 1KB/wave/i)
    const _Float16* aptr = WT + (w * 16 + col) * 32 + quad * 8;
    const float*    bptr = b_e + w * 16 + quad * 4;

    half8   af = *reinterpret_cast<const half8*>(aptr);
    floatx4 bf = *reinterpret_cast<const floatx4*>(bptr);

    for (int i = 0; i < 64; ++i) {
        int inx = (i + 1) & 63;   // wrap prefetch (iter 63 reloads i=0, harmless)
        half8   af_n = *reinterpret_cast<const half8*>(aptr + inx * 64 * 32);
        floatx4 bf_n = *reinterpret_cast<const floatx4*>(bptr + inx * 64);

        floatx4 c[4];
        c[0] = __builtin_amdgcn_mfma_f32_16x16x32_f16(af, ef[0], bf, 0, 0, 0);
        c[1] = __builtin_amdgcn_mfma_f32_16x16x32_f16(af, ef[1], bf, 0, 0, 0);
        c[2] = __builtin_amdgcn_mfma_f32_16x16x32_f16(af, ef[2], bf, 0, 0, 0);
        c[3] = __builtin_amdgcn_mfma_f32_16x16x32_f16(af, ef[3], bf, 0, 0, 0);

        floatx2 sv = {0.f, 0.f};
#pragma unroll
        for (int eb = 0; eb < 4; ++eb) {
            floatx2* cp = reinterpret_cast<floatx2*>(&c[eb]);
            sv += relu2(cp[0]) * xm[eb][0];
            sv += relu2(cp[1]) * xm[eb][1];
        }
        float s = sv[0] + sv[1];
        s += __shfl_xor(s, 32);           // fold quads 0<->2, 1<->3
        s += __shfl_xor(s, 16);           // fold quads 0<->1
        if (lane < 16) S[w][i][lane] = s; // 16 col-partials remain

        af = af_n; bf = bf_n;
    }
    __syncthreads();

    {   // cross-lane partial sums: thread (ww = tid>>6, ii = tid&63) sums 16
        int ii = tid & 63, ww = tid >> 6;
        float p = 0.f;
#pragma unroll
        for (int l = 0; l < 16; ++l) p += S[ww][ii][l];
        P[ww][ii] = p;
    }
    __syncthreads();
    if (tid < 64) aggs[tid] = P[0][tid] + P[1][tid] + P[2][tid] + P[3][tid];
    __syncthreads();

    // ---- GRU step 1: h1 = gru(nodes_row, 0); h_prev=0 => hk = bias[1] only ----
    if (tid < 192) {
        float acc = bias[tid];
#pragma unroll 4
        for (int k = 0; k < 64; ++k) acc = fmaf(xs[k], K[k * 192 + tid], acc);
        g1[tid] = acc;
    }
    __syncthreads();
    if (tid < 64) {
        float z  = sigmoidf_(g1[tid]       + bias[192 + tid]);
        float r  = sigmoidf_(g1[64 + tid]  + bias[256 + tid]);
        float hh = tanhf_  (g1[128 + tid] + r * bias[320 + tid]);
        h1s[tid] = (1.f - z) * hh;        // z*h_prev = 0
    }
    __syncthreads();

    // ---- GRU step 2: out = gru(agg_row, h1) ----
    if (tid < 192) {
        float a1 = bias[tid], a2 = bias[192 + tid];
#pragma unroll 4
        for (int k = 0; k < 64; ++k) {
            a1 = fmaf(aggs[k], K[k * 192 + tid], a1);
            a2 = fmaf(h1s[k],  R[k * 192 + tid], a2);
        }
        g1[tid] = a1; g2[tid] = a2;
    }
    __syncthreads();
    if (tid < 64) {
        float z  = sigmoidf_(g1[tid]       + g2[tid]);
        float r  = sigmoidf_(g1[64 + tid]  + g2[64 + tid]);
        float hh = tanhf_  (g1[128 + tid] + r * g2[128 + tid]);
        out[row * 64 + tid] = z * h1s[tid] + (1.f - z) * hh;
    }
}

extern "C" void kernel_launch(void* const* d_in, const int* in_sizes, int n_in,
                              void* d_out, int out_size, void* d_ws, size_t ws_size,
                              hipStream_t stream) {
    const float* nodes = (const float*)d_in[0];
    const float* edges = (const float*)d_in[1];
    const float* mask  = (const float*)d_in[2];
    const float* W_e   = (const float*)d_in[3];
    const float* b_e   = (const float*)d_in[4];
    const float* gk    = (const float*)d_in[5];
    const float* gr    = (const float*)d_in[6];
    const float* gb    = (const float*)d_in[7];
    float* out = (float*)d_out;

    _Float16* WT = (_Float16*)d_ws;   // 4096*32*2 = 256 KB

    prep_w_kernel<<<64, 256, 0, stream>>>(W_e, WT);
    fused_kernel<<<512, 256, 0, stream>>>(WT, edges, nodes, mask, b_e, gk, gr, gb, out);
}

// Round 3
// 98.502 us; speedup vs baseline: 1.0581x; 1.0148x over previous
//
#include <hip/hip_runtime.h>

typedef _Float16 half8 __attribute__((ext_vector_type(8)));
typedef float floatx4 __attribute__((ext_vector_type(4)));
typedef float floatx2 __attribute__((ext_vector_type(2)));

#define BB 8
#define NN 64
#define DD 64
#define EE 32

__device__ __forceinline__ float sigmoidf_(float x) { return 1.f / (1.f + __expf(-x)); }
__device__ __forceinline__ float tanhf_(float x) {
    float e = __expf(2.f * x);
    return (e - 1.f) / (e + 1.f);
}
__device__ __forceinline__ floatx2 relu2(floatx2 v) {
    floatx2 z = {0.f, 0.f};
    return __builtin_elementwise_max(v, z);
}

// ---------------- prep: W transpose->fp16 AND GRU step 1 ----------------
// blocks [0,64):   WT[d][k] = (fp16)W_e[k][d]   (4096 x 32, A-operand friendly)
// blocks [64,192): h1[row][d] = gru(nodes_row, h=0)  (512 rows, 4 rows/block)
__global__ void prep_kernel(const float* __restrict__ W_e,
                            const float* __restrict__ nodes,
                            const float* __restrict__ K,
                            const float* __restrict__ bias,
                            _Float16* __restrict__ WT,
                            float* __restrict__ h1) {
    const int tid = threadIdx.x;
    if (blockIdx.x < 64) {
        const int d  = blockIdx.x * 64 + (tid & 63);
        const int kq = tid >> 6;                      // 0..3 -> k = kq*8 + j
        half8 buf;
#pragma unroll
        for (int j = 0; j < 8; ++j)
            buf[j] = (_Float16)W_e[(kq * 8 + j) * 4096 + d];   // coalesced across d
        *reinterpret_cast<half8*>(WT + d * 32 + kq * 8) = buf;
    } else {
        const int blk = blockIdx.x - 64;              // 0..127
        const int rr  = tid >> 6;                     // row within block
        const int d   = tid & 63;
        const int row = blk * 4 + rr;                 // 0..511
        __shared__ float xs[4][64];
        xs[rr][d] = nodes[row * 64 + d];
        __syncthreads();
        float xz = bias[d], xr = bias[64 + d], xh = bias[128 + d];
#pragma unroll 8
        for (int k = 0; k < 64; ++k) {
            float xv = xs[rr][k];
            xz = fmaf(xv, K[k * 192 + d],       xz);
            xr = fmaf(xv, K[k * 192 + 64 + d],  xr);
            xh = fmaf(xv, K[k * 192 + 128 + d], xh);
        }
        float z  = sigmoidf_(xz + bias[192 + d]);
        float r  = sigmoidf_(xr + bias[256 + d]);
        float hh = tanhf_(xh + r * bias[320 + d]);
        h1[row * 64 + d] = (1.f - z) * hh;            // z*h_prev = 0
    }
}

// ---------------- fused: A-GEMM + relu + message + mask + j-sum + GRU step 2 ----------------
// One block per (b, i_node). 4 waves; wave w owns jj-block w (16 of 64 jj).
// Per i: C[d=i*64+jj, e] = b_e[d] + sum_k WT[d][k]*E[e][k]  (4 MFMAs/wave, depth-2 prefetch)
// epilogue: s = sum relu(C)*mask[e]*nodes[j(e)][jj]; 2 shfl folds -> 16 partials -> LDS.
// Tail: cross-wave reduce -> agg row -> GRU step 2 with precomputed h1 -> out row.
__global__ __launch_bounds__(256, 2)
void fused_kernel(const _Float16* __restrict__ WT,
                  const float* __restrict__ edges,
                  const float* __restrict__ nodes,
                  const float* __restrict__ mask,
                  const float* __restrict__ b_e,
                  const float* __restrict__ K,
                  const float* __restrict__ R,
                  const float* __restrict__ bias,
                  const float* __restrict__ h1,
                  float* __restrict__ out) {
    const int b     = blockIdx.x >> 6;
    const int inode = blockIdx.x & 63;
    const int tid   = threadIdx.x;
    const int w     = tid >> 6;
    const int lane  = tid & 63;
    const int quad  = lane >> 4;
    const int col   = lane & 15;
    const int row   = b * 64 + inode;

    __shared__ float S[4][64][17];            // 17 KB: 16 col-partials per (wave, i)
    __shared__ float P[4][64];
    __shared__ float aggs[64], h1s[64];
    __shared__ float g1[192], g2[192];

    if (tid < 64) h1s[tid] = h1[row * 64 + tid];   // step-1 result from prep

    // B-operand fragments from fp32 edges, converted in-register (loop-invariant)
    half8 ef[4];
#pragma unroll
    for (int eb = 0; eb < 4; ++eb) {
        const float* ep = edges + (b * 4096 + inode * 64 + eb * 16 + col) * 32 + quad * 8;
        floatx4 e0 = *reinterpret_cast<const floatx4*>(ep);
        floatx4 e1 = *reinterpret_cast<const floatx4*>(ep + 4);
#pragma unroll
        for (int j = 0; j < 4; ++j) {
            ef[eb][j]     = (_Float16)e0[j];
            ef[eb][4 + j] = (_Float16)e1[j];
        }
    }

    // epilogue multipliers: xm[eb][rp] = {mask*nodes for r=2rp, 2rp+1} (loop-invariant)
    floatx2 xm[4][2];
#pragma unroll
    for (int eb = 0; eb < 4; ++eb) {
        int j = eb * 16 + col;
        float mk = mask[b * 4096 + inode * 64 + j];
#pragma unroll
        for (int r = 0; r < 4; ++r) {
            int jj = w * 16 + quad * 4 + r;
            xm[eb][r >> 1][r & 1] = mk * nodes[(b * 64 + j) * 64 + jj];
        }
    }

    // A-operand: WT rows d = i*64 + w*16 + col, k = quad*8 + j
    const _Float16* aptr = WT + (w * 16 + col) * 32 + quad * 8;
    const float*    bptr = b_e + w * 16 + quad * 4;

    // depth-2 software pipeline
    half8   af0 = *reinterpret_cast<const half8*>(aptr);
    floatx4 bf0 = *reinterpret_cast<const floatx4*>(bptr);
    half8   af1 = *reinterpret_cast<const half8*>(aptr + 2048);
    floatx4 bf1 = *reinterpret_cast<const floatx4*>(bptr + 64);

    for (int i = 0; i < 64; ++i) {
        int ip2 = (i + 2) & 63;   // wrap prefetch (reloads i=0,1 at the end, harmless)
        half8   afn = *reinterpret_cast<const half8*>(aptr + ip2 * 2048);
        floatx4 bfn = *reinterpret_cast<const floatx4*>(bptr + ip2 * 64);

        floatx4 c[4];
        c[0] = __builtin_amdgcn_mfma_f32_16x16x32_f16(af0, ef[0], bf0, 0, 0, 0);
        c[1] = __builtin_amdgcn_mfma_f32_16x16x32_f16(af0, ef[1], bf0, 0, 0, 0);
        c[2] = __builtin_amdgcn_mfma_f32_16x16x32_f16(af0, ef[2], bf0, 0, 0, 0);
        c[3] = __builtin_amdgcn_mfma_f32_16x16x32_f16(af0, ef[3], bf0, 0, 0, 0);

        floatx2 sv = {0.f, 0.f};
#pragma unroll
        for (int eb = 0; eb < 4; ++eb) {
            floatx2* cp = reinterpret_cast<floatx2*>(&c[eb]);
            sv += relu2(cp[0]) * xm[eb][0];
            sv += relu2(cp[1]) * xm[eb][1];
        }
        float s = sv[0] + sv[1];
        s += __shfl_xor(s, 32);           // fold quads 0<->2, 1<->3
        s += __shfl_xor(s, 16);           // fold quads 0<->1
        if (lane < 16) S[w][i][lane] = s;

        af0 = af1; bf0 = bf1; af1 = afn; bf1 = bfn;
    }
    __syncthreads();

    {   // cross-lane partial sums: thread (ww = tid>>6, ii = tid&63) sums 16
        int ii = tid & 63, ww = tid >> 6;
        float p = 0.f;
#pragma unroll
        for (int l = 0; l < 16; ++l) p += S[ww][ii][l];
        P[ww][ii] = p;
    }
    __syncthreads();
    if (tid < 64) aggs[tid] = P[0][tid] + P[1][tid] + P[2][tid] + P[3][tid];
    __syncthreads();

    // ---- GRU step 2: out = gru(agg_row, h1) ----
    if (tid < 192) {
        float a1 = bias[tid], a2 = bias[192 + tid];
#pragma unroll 8
        for (int k = 0; k < 64; ++k) {
            a1 = fmaf(aggs[k], K[k * 192 + tid], a1);
            a2 = fmaf(h1s[k],  R[k * 192 + tid], a2);
        }
        g1[tid] = a1; g2[tid] = a2;
    }
    __syncthreads();
    if (tid < 64) {
        float z  = sigmoidf_(g1[tid]       + g2[tid]);
        float r  = sigmoidf_(g1[64 + tid]  + g2[64 + tid]);
        float hh = tanhf_  (g1[128 + tid] + r * g2[128 + tid]);
        out[row * 64 + tid] = z * h1s[tid] + (1.f - z) * hh;
    }
}

extern "C" void kernel_launch(void* const* d_in, const int* in_sizes, int n_in,
                              void* d_out, int out_size, void* d_ws, size_t ws_size,
                              hipStream_t stream) {
    const float* nodes = (const float*)d_in[0];
    const float* edges = (const float*)d_in[1];
    const float* mask  = (const float*)d_in[2];
    const float* W_e   = (const float*)d_in[3];
    const float* b_e   = (const float*)d_in[4];
    const float* gk    = (const float*)d_in[5];
    const float* gr    = (const float*)d_in[6];
    const float* gb    = (const float*)d_in[7];
    float* out = (float*)d_out;

    char* ws = (char*)d_ws;
    _Float16* WT = (_Float16*)ws;              // 4096*32*2 = 256 KB
    float*    h1 = (float*)(ws + 262144);      // 512*64*4  = 128 KB

    prep_kernel<<<192, 256, 0, stream>>>(W_e, nodes, gk, gb, WT, h1);
    fused_kernel<<<512, 256, 0, stream>>>(WT, edges, nodes, mask, b_e, gk, gr, gb, h1, out);
}